// Round 3
// baseline (147.707 us; speedup 1.0000x reference)
//
#include <hip/hip_runtime.h>
#include <math.h>

typedef __attribute__((ext_vector_type(8))) short bf16x8;           // MFMA A/B frag (8 bf16)
typedef __attribute__((ext_vector_type(8))) unsigned short u16x8;   // 16B bf16 load
typedef __attribute__((ext_vector_type(4))) float f32x4;            // MFMA C/D frag
typedef unsigned short u16;

// ---------- constants ----------
// x: [5,256,80,80] f32; loc = x[:4], glb = x[4]
// patches: 64 of [256,20,20]; S = 400; heads = 8; d = 32

__device__ __forceinline__ u16 f2bf(float f){
  unsigned u = __float_as_uint(f);
  u += 0x7fffu + ((u >> 16) & 1u);           // RNE
  return (u16)(u >> 16);
}

// bilinear 2x upsample (jax half-pixel, edge-renormalized == clamp) of an
// 80x80 plane at output row Y, cols X0..X0+3 (X0 even).
__device__ __forceinline__ float4 up4(const float* __restrict__ g, int Y, int X0){
  int jy = Y >> 1;
  int ry0, ry1; float wy0, wy1;
  if (Y & 1){ ry0 = jy; ry1 = (jy < 79) ? jy + 1 : 79; wy0 = 0.75f; wy1 = 0.25f; }
  else      { ry0 = (jy > 0) ? jy - 1 : 0; ry1 = jy;   wy0 = 0.25f; wy1 = 0.75f; }
  int jx = X0 >> 1;
  int cm1 = (jx > 0) ? jx - 1 : 0;
  int cp2 = (jx < 78) ? jx + 2 : 79;
  const float* r0 = g + ry0 * 80;
  const float* r1 = g + ry1 * 80;
  float cvm = wy0 * r0[cm1]  + wy1 * r1[cm1];
  float cv0 = wy0 * r0[jx]   + wy1 * r1[jx];
  float cv1 = wy0 * r0[jx+1] + wy1 * r1[jx+1];
  float cv2 = wy0 * r0[cp2]  + wy1 * r1[cp2];
  return make_float4(0.25f*cvm + 0.75f*cv0,
                     0.75f*cv0 + 0.25f*cv1,
                     0.25f*cv0 + 0.75f*cv1,
                     0.75f*cv1 + 0.25f*cv2);
}

// ---------- 1) positional embedding table: pos[e][s], [256][400] f32 ----------
__global__ __launch_bounds__(256) void pos_kernel(float* __restrict__ pos){
  int idx = blockIdx.x * 256 + threadIdx.x;      // [0, 102400)
  int e = idx / 400, s = idx - e * 400;
  int y = s / 20, x = s - y * 20;
  int j = e & 127;
  int m = j >> 1;
  int k = (e < 128) ? y : x;
  float v = ((float)k + 0.5f) * (6.2831853071795864769f / 20.000001f);
  float invT = exp2f(-(float)m * 0.20762050593049448f);   // 10000^(-m/64)
  float arg = v * invT;
  pos[idx] = (j & 1) ? cosf(arg) : sinf(arg);
}

// ---------- 2) feature build: Qf/Kf [n][e][s] bf16 (channel-major) ----------
__global__ __launch_bounds__(256) void feat_kernel(const float* __restrict__ xin,
                                                   const float* __restrict__ pos,
                                                   u16* __restrict__ qf,
                                                   u16* __restrict__ kf){
  int which = blockIdx.y;                         // 0: query(loc), 1: key(upsampled glb)
  int flat = blockIdx.x * 256 + threadIdx.x;      // [0, 64*256*100)
  int s4 = flat % 100;
  int rest = flat / 100;
  int e = rest & 255;
  int n = rest >> 8;
  int s0 = s4 * 4;
  int y = s0 / 20, x0 = s0 - y * 20;              // 4 consecutive x within one row
  float4 pv = *(const float4*)(pos + e * 400 + s0);
  float4 val;
  u16* dst;
  if (which == 0){
    int img = n >> 4, pi = (n >> 2) & 3, pj = n & 3;
    const float* src = xin + (((img * 256 + e) * 80) + (pi * 20 + y)) * 80 + (pj * 20 + x0);
    float4 l = *(const float4*)src;
    val.x = l.x + pv.x; val.y = l.y + pv.y; val.z = l.z + pv.z; val.w = l.w + pv.w;
    dst = qf;
  } else {
    int gi = n >> 3, gj = n & 7;
    const float* g = xin + (4 * 256 + e) * 6400;
    float4 u = up4(g, gi * 20 + y, gj * 20 + x0);
    val.x = u.x + pv.x; val.y = u.y + pv.y; val.z = u.z + pv.z; val.w = u.w + pv.w;
    dst = kf;
  }
  ushort4 o;
  o.x = f2bf(val.x); o.y = f2bf(val.y); o.z = f2bf(val.z); o.w = f2bf(val.w);
  *(ushort4*)(dst + ((n * 256 + e) * 400 + s0)) = o;
}

// ---------- 3) projection GEMM: C_n[o][s] = sum_e W[o][e]*F_n[e][s] ----------
// grid (n*4+ot, mat), 256 thr (4 waves), each wave: 16 o-rows x 400 s. K-loop e in steps of 32.
// Epilogue writes head-major layout: O[((n*8+h)*400 + s)*32 + d], h=o>>5, d=o&31.
// Q additionally scaled by (1/sqrt(32))*log2(e) so attention scores land in exp2 domain.
__global__ __launch_bounds__(256) void proj_kernel(const u16* __restrict__ qf,
                                                   const u16* __restrict__ kf,
                                                   const float* __restrict__ W,
                                                   const float* __restrict__ bvec,
                                                   u16* __restrict__ qp,
                                                   u16* __restrict__ kp){
  __shared__ u16 lds_a[64 * 32];    // W tile [o_local][e], XOR-swizzled rows of 64B
  __shared__ u16 lds_b[400 * 32];   // F tile [s][e], XOR-swizzled

  int mat = blockIdx.y;
  int bx = blockIdx.x;
  int n = bx >> 2, ot = bx & 3;
  const u16* F = mat ? kf : qf;
  u16* O = mat ? kp : qp;
  const float* Wrow = W + (mat * 256 + ot * 64) * 256;
  const float* bias = bvec + mat * 256 + ot * 64;
  float scale = mat ? 1.0f : 0.25505419776f;   // (1/sqrt(32)) * log2(e) for Q

  int tid = threadIdx.x;
  int lane = tid & 63, wave = tid >> 6;
  int lo = lane & 15, hi = lane >> 4;

  float bl[4];
  #pragma unroll
  for (int r = 0; r < 4; r++) bl[r] = bias[wave * 16 + hi * 4 + r];

  f32x4 acc[25];
  #pragma unroll
  for (int t = 0; t < 25; t++) acc[t] = (f32x4){0.f, 0.f, 0.f, 0.f};

  for (int e0 = 0; e0 < 256; e0 += 32){
    __syncthreads();
    // stage W tile: 64 rows x 32 e (fp32 -> bf16)
    for (int c = tid; c < 512; c += 256){
      int row = c >> 3, e4 = c & 7;
      float4 w4 = *(const float4*)(Wrow + row * 256 + e0 + e4 * 4);
      ushort4 pk;
      pk.x = f2bf(w4.x); pk.y = f2bf(w4.y); pk.z = f2bf(w4.z); pk.w = f2bf(w4.w);
      int idx = row * 32 + ((e4 * 4) ^ ((row & 3) << 3));
      *(ushort4*)(lds_a + idx) = pk;
    }
    // stage F tile: 32 e-rows x 400 s, transposed into [s][e] with swizzle
    for (int c = tid; c < 1600; c += 256){
      int er = c & 31, s8 = c >> 5;
      u16x8 v = *(const u16x8*)(F + ((n * 256 + e0 + er) * 400 + s8 * 8));
      #pragma unroll
      for (int j = 0; j < 8; j++){
        int s = s8 * 8 + j;
        lds_b[s * 32 + (er ^ ((s & 3) << 3))] = v[j];
      }
    }
    __syncthreads();
    // compute: A-frag for this wave's 16 o rows, 25 s-tiles
    bf16x8 afr = *(const bf16x8*)(lds_a + (wave * 16 + lo) * 32 + ((hi * 8) ^ ((lo & 3) << 3)));
    #pragma unroll
    for (int st = 0; st < 25; st++){
      bf16x8 bfr = *(const bf16x8*)(lds_b + (st * 16 + lo) * 32 + ((hi * 8) ^ ((lo & 3) << 3)));
      acc[st] = __builtin_amdgcn_mfma_f32_16x16x32_bf16(afr, bfr, acc[st], 0, 0, 0);
    }
  }
  // epilogue: o_local = wave*16 + hi*4 + r; 4 consecutive d -> one b64 store
  int o_loc = wave * 16 + hi * 4;
  int hh = ot * 2 + (o_loc >> 5);
  int d0 = o_loc & 31;
  #pragma unroll
  for (int st = 0; st < 25; st++){
    int s = st * 16 + lo;
    ushort4 pk;
    pk.x = f2bf((acc[st][0] + bl[0]) * scale);
    pk.y = f2bf((acc[st][1] + bl[1]) * scale);
    pk.z = f2bf((acc[st][2] + bl[2]) * scale);
    pk.w = f2bf((acc[st][3] + bl[3]) * scale);
    *(ushort4*)(O + ((size_t)((n * 8 + hh) * 400 + s)) * 32 + d0) = pk;
  }
}

// ---------- 4) fused scores+softmax+colsum: per (n,h) block ----------
// colsum[n][h][s] = sum_l softmax_s(scores[n,h,l,:])[s]
// Q,K staged in LDS once. K rows padded to 40 u16 (80B) -> conflict-free
// ds_read_b128 frag reads. No max subtraction: scores are O(+-5), softmax is
// shift-invariant, exp2 overflow needs |score| > ~120. Q pre-scaled by log2e.
__global__ __launch_bounds__(256) void attn_kernel(const u16* __restrict__ qp,
                                                   const u16* __restrict__ kp,
                                                   float* __restrict__ colsum){
  __shared__ u16 q_lds[400 * 32];   // [l][d=32], unpadded (1 read per lt, conflicts negligible)
  __shared__ u16 k_lds[400 * 40];   // [s][d=32 in 40-u16 padded rows]
  __shared__ float cs[400];

  int bx = blockIdx.x;
  int n = bx >> 3, h = bx & 7;
  int tid = threadIdx.x;
  for (int i = tid; i < 400; i += 256) cs[i] = 0.f;

  const u16* qb = qp + (size_t)(n * 8 + h) * 400 * 32;
  const u16* kb = kp + (size_t)(n * 8 + h) * 400 * 32;

  // stage Q + K: 800 rows x 4 chunks of 16B; global reads fully coalesced
  for (int c = tid; c < 3200; c += 256){
    int chunk = c & 3, row = c >> 2;           // row 0..799
    if (row < 400){
      u16x8 v = *(const u16x8*)(qb + row * 32 + chunk * 8);
      *(u16x8*)(q_lds + row * 32 + chunk * 8) = v;
    } else {
      int r2 = row - 400;
      u16x8 v = *(const u16x8*)(kb + r2 * 32 + chunk * 8);
      *(u16x8*)(k_lds + r2 * 40 + chunk * 8) = v;
    }
  }
  __syncthreads();

  int lane = tid & 63, wave = tid >> 6;
  int lo = lane & 15, hi = lane >> 4;

  // per-lane colsum accumulators: s = st*16 + hi*4 + r (constant over lt)
  float csacc[25][4];
  #pragma unroll
  for (int st = 0; st < 25; st++){
    #pragma unroll
    for (int r = 0; r < 4; r++) csacc[st][r] = 0.f;
  }

  for (int lt = wave; lt < 25; lt += 4){
    // swapped product: D[s][l] = K(16s x 32d) * Q^T
    bf16x8 qfr = *(const bf16x8*)(q_lds + (lt * 16 + lo) * 32 + hi * 8);
    f32x4 sc[25];
    #pragma unroll
    for (int st = 0; st < 25; st++){
      bf16x8 kfr = *(const bf16x8*)(k_lds + (st * 16 + lo) * 40 + hi * 8);
      sc[st] = __builtin_amdgcn_mfma_f32_16x16x32_bf16(kfr, qfr, (f32x4){0.f, 0.f, 0.f, 0.f}, 0, 0, 0);
    }
    // lane holds scores (already x log2e) for q-row l = lt*16+lo at s = st*16 + hi*4 + r
    float z0 = 0.f, z1 = 0.f, z2 = 0.f, z3 = 0.f;
    #pragma unroll
    for (int st = 0; st < 25; st++){
      float p0 = exp2f(sc[st][0]);
      float p1 = exp2f(sc[st][1]);
      float p2 = exp2f(sc[st][2]);
      float p3 = exp2f(sc[st][3]);
      sc[st][0] = p0; sc[st][1] = p1; sc[st][2] = p2; sc[st][3] = p3;
      z0 += p0; z1 += p1; z2 += p2; z3 += p3;
    }
    float z = (z0 + z1) + (z2 + z3);
    z += __shfl_xor(z, 16, 64);
    z += __shfl_xor(z, 32, 64);
    float invz = 1.0f / z;
    #pragma unroll
    for (int st = 0; st < 25; st++){
      #pragma unroll
      for (int r = 0; r < 4; r++){
        csacc[st][r] += sc[st][r] * invz;
      }
    }
  }

  // one reduction over the 16 l-lanes (lo) at the end, then one LDS atomic
  #pragma unroll
  for (int st = 0; st < 25; st++){
    #pragma unroll
    for (int r = 0; r < 4; r++){
      float wv = csacc[st][r];
      wv += __shfl_xor(wv, 1, 64);
      wv += __shfl_xor(wv, 2, 64);
      wv += __shfl_xor(wv, 4, 64);
      wv += __shfl_xor(wv, 8, 64);
      if (lo == 0) atomicAdd(&cs[st * 16 + hi * 4 + r], wv);
    }
  }
  __syncthreads();
  for (int i = tid; i < 400; i += 256)
    colsum[(n * 8 + h) * 400 + i] = cs[i];
}

// ---------- 5) importance: imp[n][s] = sigmoid(sal_w * mean + sal_b) ----------
__global__ __launch_bounds__(256) void imp_kernel(const float* __restrict__ colsum,
                                                  const float* __restrict__ sal_w,
                                                  const float* __restrict__ sal_b,
                                                  float* __restrict__ imp){
  int idx = blockIdx.x * 256 + threadIdx.x;   // [0, 25600)
  int n = idx / 400, s = idx - n * 400;
  float sum = 0.f;
  #pragma unroll
  for (int h = 0; h < 8; h++) sum += colsum[(n * 8 + h) * 400 + s];
  float aw = sum * (1.0f / 3200.0f);
  float zz = sal_w[0] * aw + sal_b[0];
  imp[idx] = 1.0f / (1.0f + __expf(-zz));
}

// ---------- 6) final merge: out[e][Y][X] = loc*0.6*imp + 0.5*up_glb ----------
__global__ __launch_bounds__(256) void out_kernel(const float* __restrict__ xin,
                                                  const float* __restrict__ imp,
                                                  float* __restrict__ out){
  int flat = blockIdx.x * 256 + threadIdx.x;  // [0, 256*160*40)
  int x4 = flat % 40;
  int rest = flat / 40;
  int Y = rest % 160;
  int e = rest / 160;
  int X0 = x4 * 4;
  int a = (Y >= 80) ? 1 : 0;
  int bq = (X0 >= 80) ? 1 : 0;
  int yy = Y - a * 80, xx = X0 - bq * 80;
  int pi = yy / 20, y = yy - pi * 20;
  int pj = xx / 20, x0 = xx - pj * 20;
  int img = a * 2 + bq;
  int nn = img * 16 + pi * 4 + pj;
  int s0 = y * 20 + x0;
  float4 l4 = *(const float4*)(xin + ((img * 256 + e) * 80 + yy) * 80 + xx);
  float4 i4 = *(const float4*)(imp + nn * 400 + s0);
  const float* g = xin + (4 * 256 + e) * 6400;
  float4 u4 = up4(g, Y, X0);
  float4 o;
  o.x = l4.x * (0.6f * i4.x) + 0.5f * u4.x;
  o.y = l4.y * (0.6f * i4.y) + 0.5f * u4.y;
  o.z = l4.z * (0.6f * i4.z) + 0.5f * u4.z;
  o.w = l4.w * (0.6f * i4.w) + 0.5f * u4.w;
  *(float4*)(out + (e * 160 + Y) * 160 + X0) = o;
}

// ---------- launch ----------
extern "C" void kernel_launch(void* const* d_in, const int* in_sizes, int n_in,
                              void* d_out, int out_size, void* d_ws, size_t ws_size,
                              hipStream_t stream) {
  const float* x      = (const float*)d_in[0];   // [5,256,80,80]
  const float* W      = (const float*)d_in[1];   // [768,256]
  const float* bvec   = (const float*)d_in[2];   // [768]
  const float* sal_w  = (const float*)d_in[3];
  const float* sal_b  = (const float*)d_in[4];
  float* out = (float*)d_out;                    // [256,160,160]

  // ws layout (all offsets 16B-aligned)
  const size_t POS_OFF = 0;                         // 256*400*4      =   409600
  const size_t QF_OFF  = 409600;                    // 64*256*400*2   = 13107200
  const size_t KF_OFF  = QF_OFF + 13107200;
  const size_t QP_OFF  = KF_OFF + 13107200;
  const size_t KP_OFF  = QP_OFF + 13107200;
  const size_t CS_OFF  = KP_OFF + 13107200;         // 64*8*400*4     =   819200
  const size_t IMP_OFF = CS_OFF + 819200;           // 64*400*4       =   102400
  const size_t NEED    = IMP_OFF + 102400;          // 53,760,000 B
  if (ws_size < NEED) return;   // insufficient scratch: leave output poisoned (clean fail)

  char* ws = (char*)d_ws;
  float* pos    = (float*)(ws + POS_OFF);
  u16*   qf     = (u16*)(ws + QF_OFF);
  u16*   kf     = (u16*)(ws + KF_OFF);
  u16*   qp     = (u16*)(ws + QP_OFF);
  u16*   kp     = (u16*)(ws + KP_OFF);
  float* colsum = (float*)(ws + CS_OFF);
  float* imp    = (float*)(ws + IMP_OFF);

  pos_kernel<<<400, 256, 0, stream>>>(pos);
  feat_kernel<<<dim3(6400, 2), 256, 0, stream>>>(x, pos, qf, kf);
  proj_kernel<<<dim3(256, 2), 256, 0, stream>>>(qf, kf, W, bvec, qp, kp);
  attn_kernel<<<512, 256, 0, stream>>>(qp, kp, colsum);
  imp_kernel<<<100, 256, 0, stream>>>(colsum, sal_w, sal_b, imp);
  out_kernel<<<6400, 256, 0, stream>>>(x, imp, out);
}

// Round 4
// 144.481 us; speedup vs baseline: 1.0223x; 1.0223x over previous
//
#include <hip/hip_runtime.h>
#include <math.h>

typedef __attribute__((ext_vector_type(8))) short bf16x8;           // MFMA A/B frag (8 bf16)
typedef __attribute__((ext_vector_type(8))) unsigned short u16x8;   // 16B bf16 load
typedef __attribute__((ext_vector_type(4))) float f32x4;            // MFMA C/D frag
typedef unsigned short u16;

// ---------- constants ----------
// x: [5,256,80,80] f32; loc = x[:4], glb = x[4]
// patches: 64 of [256,20,20]; S = 400; heads = 8; d = 32

__device__ __forceinline__ u16 f2bf(float f){
  unsigned u = __float_as_uint(f);
  u += 0x7fffu + ((u >> 16) & 1u);           // RNE
  return (u16)(u >> 16);
}

// bilinear 2x upsample (jax half-pixel, edge-renormalized == clamp) of an
// 80x80 plane at output row Y, cols X0..X0+3 (X0 even).
__device__ __forceinline__ float4 up4(const float* __restrict__ g, int Y, int X0){
  int jy = Y >> 1;
  int ry0, ry1; float wy0, wy1;
  if (Y & 1){ ry0 = jy; ry1 = (jy < 79) ? jy + 1 : 79; wy0 = 0.75f; wy1 = 0.25f; }
  else      { ry0 = (jy > 0) ? jy - 1 : 0; ry1 = jy;   wy0 = 0.25f; wy1 = 0.75f; }
  int jx = X0 >> 1;
  int cm1 = (jx > 0) ? jx - 1 : 0;
  int cp2 = (jx < 78) ? jx + 2 : 79;
  const float* r0 = g + ry0 * 80;
  const float* r1 = g + ry1 * 80;
  float cvm = wy0 * r0[cm1]  + wy1 * r1[cm1];
  float cv0 = wy0 * r0[jx]   + wy1 * r1[jx];
  float cv1 = wy0 * r0[jx+1] + wy1 * r1[jx+1];
  float cv2 = wy0 * r0[cp2]  + wy1 * r1[cp2];
  return make_float4(0.25f*cvm + 0.75f*cv0,
                     0.75f*cv0 + 0.25f*cv1,
                     0.25f*cv0 + 0.75f*cv1,
                     0.75f*cv1 + 0.25f*cv2);
}

// ---------- 1) positional embedding table: pos[e][s], [256][400] f32 ----------
__global__ __launch_bounds__(256) void pos_kernel(float* __restrict__ pos){
  int idx = blockIdx.x * 256 + threadIdx.x;      // [0, 102400)
  int e = idx / 400, s = idx - e * 400;
  int y = s / 20, x = s - y * 20;
  int j = e & 127;
  int m = j >> 1;
  int k = (e < 128) ? y : x;
  float v = ((float)k + 0.5f) * (6.2831853071795864769f / 20.000001f);
  float invT = exp2f(-(float)m * 0.20762050593049448f);   // 10000^(-m/64)
  float arg = v * invT;
  pos[idx] = (j & 1) ? cosf(arg) : sinf(arg);
}

// ---------- 2) feature build: Qf/Kf [n][e][s] bf16 (channel-major) ----------
__global__ __launch_bounds__(256) void feat_kernel(const float* __restrict__ xin,
                                                   const float* __restrict__ pos,
                                                   u16* __restrict__ qf,
                                                   u16* __restrict__ kf){
  int which = blockIdx.y;                         // 0: query(loc), 1: key(upsampled glb)
  int flat = blockIdx.x * 256 + threadIdx.x;      // [0, 64*256*100)
  int s4 = flat % 100;
  int rest = flat / 100;
  int e = rest & 255;
  int n = rest >> 8;
  int s0 = s4 * 4;
  int y = s0 / 20, x0 = s0 - y * 20;              // 4 consecutive x within one row
  float4 pv = *(const float4*)(pos + e * 400 + s0);
  float4 val;
  u16* dst;
  if (which == 0){
    int img = n >> 4, pi = (n >> 2) & 3, pj = n & 3;
    const float* src = xin + (((img * 256 + e) * 80) + (pi * 20 + y)) * 80 + (pj * 20 + x0);
    float4 l = *(const float4*)src;
    val.x = l.x + pv.x; val.y = l.y + pv.y; val.z = l.z + pv.z; val.w = l.w + pv.w;
    dst = qf;
  } else {
    int gi = n >> 3, gj = n & 7;
    const float* g = xin + (4 * 256 + e) * 6400;
    float4 u = up4(g, gi * 20 + y, gj * 20 + x0);
    val.x = u.x + pv.x; val.y = u.y + pv.y; val.z = u.z + pv.z; val.w = u.w + pv.w;
    dst = kf;
  }
  ushort4 o;
  o.x = f2bf(val.x); o.y = f2bf(val.y); o.z = f2bf(val.z); o.w = f2bf(val.w);
  *(ushort4*)(dst + ((n * 256 + e) * 400 + s0)) = o;
}

// ---------- 3) projection GEMM: C_n[o][s] = sum_e W[o][e]*F_n[e][s] ----------
// grid (n*4+ot, mat), 256 thr (4 waves), each wave: 16 o-rows x 400 s. K-loop e in steps of 32.
// Epilogue writes head-major layout: O[((n*8+h)*400 + s)*32 + d], h=o>>5, d=o&31.
// Q additionally scaled by (1/sqrt(32))*log2(e) so attention scores land in exp2 domain.
__global__ __launch_bounds__(256) void proj_kernel(const u16* __restrict__ qf,
                                                   const u16* __restrict__ kf,
                                                   const float* __restrict__ W,
                                                   const float* __restrict__ bvec,
                                                   u16* __restrict__ qp,
                                                   u16* __restrict__ kp){
  __shared__ u16 lds_a[64 * 32];    // W tile [o_local][e], XOR-swizzled rows of 64B
  __shared__ u16 lds_b[400 * 32];   // F tile [s][e], XOR-swizzled

  int mat = blockIdx.y;
  int bx = blockIdx.x;
  int n = bx >> 2, ot = bx & 3;
  const u16* F = mat ? kf : qf;
  u16* O = mat ? kp : qp;
  const float* Wrow = W + (mat * 256 + ot * 64) * 256;
  const float* bias = bvec + mat * 256 + ot * 64;
  float scale = mat ? 1.0f : 0.25505419776f;   // (1/sqrt(32)) * log2(e) for Q

  int tid = threadIdx.x;
  int lane = tid & 63, wave = tid >> 6;
  int lo = lane & 15, hi = lane >> 4;

  float bl[4];
  #pragma unroll
  for (int r = 0; r < 4; r++) bl[r] = bias[wave * 16 + hi * 4 + r];

  f32x4 acc[25];
  #pragma unroll
  for (int t = 0; t < 25; t++) acc[t] = (f32x4){0.f, 0.f, 0.f, 0.f};

  for (int e0 = 0; e0 < 256; e0 += 32){
    __syncthreads();
    // stage W tile: 64 rows x 32 e (fp32 -> bf16)
    for (int c = tid; c < 512; c += 256){
      int row = c >> 3, e4 = c & 7;
      float4 w4 = *(const float4*)(Wrow + row * 256 + e0 + e4 * 4);
      ushort4 pk;
      pk.x = f2bf(w4.x); pk.y = f2bf(w4.y); pk.z = f2bf(w4.z); pk.w = f2bf(w4.w);
      int idx = row * 32 + ((e4 * 4) ^ ((row & 3) << 3));
      *(ushort4*)(lds_a + idx) = pk;
    }
    // stage F tile: 32 e-rows x 400 s, transposed into [s][e] with swizzle
    for (int c = tid; c < 1600; c += 256){
      int er = c & 31, s8 = c >> 5;
      u16x8 v = *(const u16x8*)(F + ((n * 256 + e0 + er) * 400 + s8 * 8));
      #pragma unroll
      for (int j = 0; j < 8; j++){
        int s = s8 * 8 + j;
        lds_b[s * 32 + (er ^ ((s & 3) << 3))] = v[j];
      }
    }
    __syncthreads();
    // compute: A-frag for this wave's 16 o rows, 25 s-tiles
    bf16x8 afr = *(const bf16x8*)(lds_a + (wave * 16 + lo) * 32 + ((hi * 8) ^ ((lo & 3) << 3)));
    #pragma unroll
    for (int st = 0; st < 25; st++){
      bf16x8 bfr = *(const bf16x8*)(lds_b + (st * 16 + lo) * 32 + ((hi * 8) ^ ((lo & 3) << 3)));
      acc[st] = __builtin_amdgcn_mfma_f32_16x16x32_bf16(afr, bfr, acc[st], 0, 0, 0);
    }
  }
  // epilogue: o_local = wave*16 + hi*4 + r; 4 consecutive d -> one b64 store
  int o_loc = wave * 16 + hi * 4;
  int hh = ot * 2 + (o_loc >> 5);
  int d0 = o_loc & 31;
  #pragma unroll
  for (int st = 0; st < 25; st++){
    int s = st * 16 + lo;
    ushort4 pk;
    pk.x = f2bf((acc[st][0] + bl[0]) * scale);
    pk.y = f2bf((acc[st][1] + bl[1]) * scale);
    pk.z = f2bf((acc[st][2] + bl[2]) * scale);
    pk.w = f2bf((acc[st][3] + bl[3]) * scale);
    *(ushort4*)(O + ((size_t)((n * 8 + hh) * 400 + s)) * 32 + d0) = pk;
  }
}

// ---------- 4) fused scores+softmax+colsum: per (n,h) block, TWO-PASS ----------
// colsum[n][h][s] = sum_l exp2(S[l,s]) * invz[l]   (Q pre-scaled by log2e, no max:
// scores are O(+-5), exp2 overflow needs |score|>120)
// Pass A: invz[l] only (transient score regs). Pass B: recompute scores (MFMA is
// ~3% util, recompute is free) and accumulate csacc with scores consumed
// immediately. Peak live regs ~130 vs ~312 in the one-pass version -> 2+ waves/SIMD.
// K in LDS (pad-40 rows); Q read per-lt from global (1KB coalesced, L1-hot).
__global__ __launch_bounds__(256, 2) void attn_kernel(const u16* __restrict__ qp,
                                                      const u16* __restrict__ kp,
                                                      float* __restrict__ colsum){
  __shared__ u16 k_lds[400 * 40];   // [s][d=32 in 40-u16 padded rows] = 32000 B
  __shared__ float cs[400];

  int bx = blockIdx.x;
  int n = bx >> 3, h = bx & 7;
  int tid = threadIdx.x;
  for (int i = tid; i < 400; i += 256) cs[i] = 0.f;

  const u16* qb = qp + (size_t)(n * 8 + h) * 400 * 32;
  const u16* kb = kp + (size_t)(n * 8 + h) * 400 * 32;

  // stage K: 400 rows x 4 chunks of 16B; global reads fully coalesced
  for (int c = tid; c < 1600; c += 256){
    int chunk = c & 3, row = c >> 2;
    u16x8 v = *(const u16x8*)(kb + row * 32 + chunk * 8);
    *(u16x8*)(k_lds + row * 40 + chunk * 8) = v;
  }
  __syncthreads();

  int lane = tid & 63, wave = tid >> 6;
  int lo = lane & 15, hi = lane >> 4;

  // ---- pass A: per-q-row softmax denominators (transient regs only) ----
  float invz[7];
  #pragma unroll
  for (int i = 0; i < 7; i++){
    int lt = wave + i * 4;
    invz[i] = 0.f;
    if (lt < 25){
      bf16x8 qfr = *(const bf16x8*)(qb + (lt * 16 + lo) * 32 + hi * 8);
      float z0 = 0.f, z1 = 0.f, z2 = 0.f, z3 = 0.f;
      #pragma unroll
      for (int st = 0; st < 25; st++){
        bf16x8 kfr = *(const bf16x8*)(k_lds + (st * 16 + lo) * 40 + hi * 8);
        f32x4 sc = __builtin_amdgcn_mfma_f32_16x16x32_bf16(kfr, qfr, (f32x4){0.f,0.f,0.f,0.f}, 0, 0, 0);
        z0 += exp2f(sc[0]);
        z1 += exp2f(sc[1]);
        z2 += exp2f(sc[2]);
        z3 += exp2f(sc[3]);
      }
      float z = (z0 + z1) + (z2 + z3);
      z += __shfl_xor(z, 16, 64);
      z += __shfl_xor(z, 32, 64);
      invz[i] = 1.0f / z;
    }
  }

  // ---- pass B: recompute scores, accumulate colsum partials ----
  float csacc[25][4];
  #pragma unroll
  for (int st = 0; st < 25; st++){
    #pragma unroll
    for (int r = 0; r < 4; r++) csacc[st][r] = 0.f;
  }

  #pragma unroll
  for (int i = 0; i < 7; i++){
    int lt = wave + i * 4;
    if (lt < 25){
      bf16x8 qfr = *(const bf16x8*)(qb + (lt * 16 + lo) * 32 + hi * 8);
      float w = invz[i];
      #pragma unroll
      for (int st = 0; st < 25; st++){
        bf16x8 kfr = *(const bf16x8*)(k_lds + (st * 16 + lo) * 40 + hi * 8);
        f32x4 sc = __builtin_amdgcn_mfma_f32_16x16x32_bf16(kfr, qfr, (f32x4){0.f,0.f,0.f,0.f}, 0, 0, 0);
        csacc[st][0] += exp2f(sc[0]) * w;
        csacc[st][1] += exp2f(sc[1]) * w;
        csacc[st][2] += exp2f(sc[2]) * w;
        csacc[st][3] += exp2f(sc[3]) * w;
      }
    }
  }

  // one reduction over the 16 l-lanes (lo) at the end, then one LDS atomic
  #pragma unroll
  for (int st = 0; st < 25; st++){
    #pragma unroll
    for (int r = 0; r < 4; r++){
      float wv = csacc[st][r];
      wv += __shfl_xor(wv, 1, 64);
      wv += __shfl_xor(wv, 2, 64);
      wv += __shfl_xor(wv, 4, 64);
      wv += __shfl_xor(wv, 8, 64);
      if (lo == 0) atomicAdd(&cs[st * 16 + hi * 4 + r], wv);
    }
  }
  __syncthreads();
  for (int i = tid; i < 400; i += 256)
    colsum[(n * 8 + h) * 400 + i] = cs[i];
}

// ---------- 5) importance: imp[n][s] = sigmoid(sal_w * mean + sal_b) ----------
__global__ __launch_bounds__(256) void imp_kernel(const float* __restrict__ colsum,
                                                  const float* __restrict__ sal_w,
                                                  const float* __restrict__ sal_b,
                                                  float* __restrict__ imp){
  int idx = blockIdx.x * 256 + threadIdx.x;   // [0, 25600)
  int n = idx / 400, s = idx - n * 400;
  float sum = 0.f;
  #pragma unroll
  for (int h = 0; h < 8; h++) sum += colsum[(n * 8 + h) * 400 + s];
  float aw = sum * (1.0f / 3200.0f);
  float zz = sal_w[0] * aw + sal_b[0];
  imp[idx] = 1.0f / (1.0f + __expf(-zz));
}

// ---------- 6) final merge: out[e][Y][X] = loc*0.6*imp + 0.5*up_glb ----------
__global__ __launch_bounds__(256) void out_kernel(const float* __restrict__ xin,
                                                  const float* __restrict__ imp,
                                                  float* __restrict__ out){
  int flat = blockIdx.x * 256 + threadIdx.x;  // [0, 256*160*40)
  int x4 = flat % 40;
  int rest = flat / 40;
  int Y = rest % 160;
  int e = rest / 160;
  int X0 = x4 * 4;
  int a = (Y >= 80) ? 1 : 0;
  int bq = (X0 >= 80) ? 1 : 0;
  int yy = Y - a * 80, xx = X0 - bq * 80;
  int pi = yy / 20, y = yy - pi * 20;
  int pj = xx / 20, x0 = xx - pj * 20;
  int img = a * 2 + bq;
  int nn = img * 16 + pi * 4 + pj;
  int s0 = y * 20 + x0;
  float4 l4 = *(const float4*)(xin + ((img * 256 + e) * 80 + yy) * 80 + xx);
  float4 i4 = *(const float4*)(imp + nn * 400 + s0);
  const float* g = xin + (4 * 256 + e) * 6400;
  float4 u4 = up4(g, Y, X0);
  float4 o;
  o.x = l4.x * (0.6f * i4.x) + 0.5f * u4.x;
  o.y = l4.y * (0.6f * i4.y) + 0.5f * u4.y;
  o.z = l4.z * (0.6f * i4.z) + 0.5f * u4.z;
  o.w = l4.w * (0.6f * i4.w) + 0.5f * u4.w;
  *(float4*)(out + (e * 160 + Y) * 160 + X0) = o;
}

// ---------- launch ----------
extern "C" void kernel_launch(void* const* d_in, const int* in_sizes, int n_in,
                              void* d_out, int out_size, void* d_ws, size_t ws_size,
                              hipStream_t stream) {
  const float* x      = (const float*)d_in[0];   // [5,256,80,80]
  const float* W      = (const float*)d_in[1];   // [768,256]
  const float* bvec   = (const float*)d_in[2];   // [768]
  const float* sal_w  = (const float*)d_in[3];
  const float* sal_b  = (const float*)d_in[4];
  float* out = (float*)d_out;                    // [256,160,160]

  // ws layout (all offsets 16B-aligned)
  const size_t POS_OFF = 0;                         // 256*400*4      =   409600
  const size_t QF_OFF  = 409600;                    // 64*256*400*2   = 13107200
  const size_t KF_OFF  = QF_OFF + 13107200;
  const size_t QP_OFF  = KF_OFF + 13107200;
  const size_t KP_OFF  = QP_OFF + 13107200;
  const size_t CS_OFF  = KP_OFF + 13107200;         // 64*8*400*4     =   819200
  const size_t IMP_OFF = CS_OFF + 819200;           // 64*400*4       =   102400
  const size_t NEED    = IMP_OFF + 102400;          // 53,760,000 B
  if (ws_size < NEED) return;   // insufficient scratch: leave output poisoned (clean fail)

  char* ws = (char*)d_ws;
  float* pos    = (float*)(ws + POS_OFF);
  u16*   qf     = (u16*)(ws + QF_OFF);
  u16*   kf     = (u16*)(ws + KF_OFF);
  u16*   qp     = (u16*)(ws + QP_OFF);
  u16*   kp     = (u16*)(ws + KP_OFF);
  float* colsum = (float*)(ws + CS_OFF);
  float* imp    = (float*)(ws + IMP_OFF);

  pos_kernel<<<400, 256, 0, stream>>>(pos);
  feat_kernel<<<dim3(6400, 2), 256, 0, stream>>>(x, pos, qf, kf);
  proj_kernel<<<dim3(256, 2), 256, 0, stream>>>(qf, kf, W, bvec, qp, kp);
  attn_kernel<<<512, 256, 0, stream>>>(qp, kp, colsum);
  imp_kernel<<<100, 256, 0, stream>>>(colsum, sal_w, sal_b, imp);
  out_kernel<<<6400, 256, 0, stream>>>(x, imp, out);
}

// Round 5
// 124.892 us; speedup vs baseline: 1.1827x; 1.1568x over previous
//
#include <hip/hip_runtime.h>
#include <math.h>

typedef __attribute__((ext_vector_type(8))) short bf16x8;           // MFMA A/B frag (8 bf16)
typedef __attribute__((ext_vector_type(8))) unsigned short u16x8;   // 16B bf16 load
typedef __attribute__((ext_vector_type(4))) float f32x4;            // MFMA C/D frag
typedef unsigned short u16;

// ---------- constants ----------
// x: [5,256,80,80] f32; loc = x[:4], glb = x[4]
// patches: 64 of [256,20,20]; S = 400; heads = 8; d = 32

__device__ __forceinline__ u16 f2bf(float f){
  unsigned u = __float_as_uint(f);
  u += 0x7fffu + ((u >> 16) & 1u);           // RNE
  return (u16)(u >> 16);
}

// bilinear 2x upsample (jax half-pixel, edge-renormalized == clamp) of an
// 80x80 plane at output row Y, cols X0..X0+3 (X0 even).
__device__ __forceinline__ float4 up4(const float* __restrict__ g, int Y, int X0){
  int jy = Y >> 1;
  int ry0, ry1; float wy0, wy1;
  if (Y & 1){ ry0 = jy; ry1 = (jy < 79) ? jy + 1 : 79; wy0 = 0.75f; wy1 = 0.25f; }
  else      { ry0 = (jy > 0) ? jy - 1 : 0; ry1 = jy;   wy0 = 0.25f; wy1 = 0.75f; }
  int jx = X0 >> 1;
  int cm1 = (jx > 0) ? jx - 1 : 0;
  int cp2 = (jx < 78) ? jx + 2 : 79;
  const float* r0 = g + ry0 * 80;
  const float* r1 = g + ry1 * 80;
  float cvm = wy0 * r0[cm1]  + wy1 * r1[cm1];
  float cv0 = wy0 * r0[jx]   + wy1 * r1[jx];
  float cv1 = wy0 * r0[jx+1] + wy1 * r1[jx+1];
  float cv2 = wy0 * r0[cp2]  + wy1 * r1[cp2];
  return make_float4(0.25f*cvm + 0.75f*cv0,
                     0.75f*cv0 + 0.25f*cv1,
                     0.25f*cv0 + 0.75f*cv1,
                     0.75f*cv1 + 0.25f*cv2);
}

// ---------- 1) positional embedding table: pos[e][s], [256][400] f32 ----------
__global__ __launch_bounds__(256) void pos_kernel(float* __restrict__ pos){
  int idx = blockIdx.x * 256 + threadIdx.x;      // [0, 102400)
  int e = idx / 400, s = idx - e * 400;
  int y = s / 20, x = s - y * 20;
  int j = e & 127;
  int m = j >> 1;
  int k = (e < 128) ? y : x;
  float v = ((float)k + 0.5f) * (6.2831853071795864769f / 20.000001f);
  float invT = exp2f(-(float)m * 0.20762050593049448f);   // 10000^(-m/64)
  float arg = v * invT;
  pos[idx] = (j & 1) ? cosf(arg) : sinf(arg);
}

// ---------- 2) feature build: Qf/Kf [n][e][s] bf16 (channel-major) ----------
__global__ __launch_bounds__(256) void feat_kernel(const float* __restrict__ xin,
                                                   const float* __restrict__ pos,
                                                   u16* __restrict__ qf,
                                                   u16* __restrict__ kf){
  int which = blockIdx.y;                         // 0: query(loc), 1: key(upsampled glb)
  int flat = blockIdx.x * 256 + threadIdx.x;      // [0, 64*256*100)
  int s4 = flat % 100;
  int rest = flat / 100;
  int e = rest & 255;
  int n = rest >> 8;
  int s0 = s4 * 4;
  int y = s0 / 20, x0 = s0 - y * 20;              // 4 consecutive x within one row
  float4 pv = *(const float4*)(pos + e * 400 + s0);
  float4 val;
  u16* dst;
  if (which == 0){
    int img = n >> 4, pi = (n >> 2) & 3, pj = n & 3;
    const float* src = xin + (((img * 256 + e) * 80) + (pi * 20 + y)) * 80 + (pj * 20 + x0);
    float4 l = *(const float4*)src;
    val.x = l.x + pv.x; val.y = l.y + pv.y; val.z = l.z + pv.z; val.w = l.w + pv.w;
    dst = qf;
  } else {
    int gi = n >> 3, gj = n & 7;
    const float* g = xin + (4 * 256 + e) * 6400;
    float4 u = up4(g, gi * 20 + y, gj * 20 + x0);
    val.x = u.x + pv.x; val.y = u.y + pv.y; val.z = u.z + pv.z; val.w = u.w + pv.w;
    dst = kf;
  }
  ushort4 o;
  o.x = f2bf(val.x); o.y = f2bf(val.y); o.z = f2bf(val.z); o.w = f2bf(val.w);
  *(ushort4*)(dst + ((n * 256 + e) * 400 + s0)) = o;
}

// ---------- 3) projection GEMM: C_n[o][s] = sum_e W[o][e]*F_n[e][s] ----------
// grid (n*4+ot, mat), 256 thr (4 waves), each wave: 16 o-rows x 400 s. K-loop e in steps of 32.
// Epilogue writes head-major layout: O[((n*8+h)*400 + s)*32 + d], h=o>>5, d=o&31.
// Q additionally scaled by (1/sqrt(32))*log2(e) so attention scores land in exp2 domain.
__global__ __launch_bounds__(256) void proj_kernel(const u16* __restrict__ qf,
                                                   const u16* __restrict__ kf,
                                                   const float* __restrict__ W,
                                                   const float* __restrict__ bvec,
                                                   u16* __restrict__ qp,
                                                   u16* __restrict__ kp){
  __shared__ u16 lds_a[64 * 32];    // W tile [o_local][e], XOR-swizzled rows of 64B
  __shared__ u16 lds_b[400 * 32];   // F tile [s][e], XOR-swizzled

  int mat = blockIdx.y;
  int bx = blockIdx.x;
  int n = bx >> 2, ot = bx & 3;
  const u16* F = mat ? kf : qf;
  u16* O = mat ? kp : qp;
  const float* Wrow = W + (mat * 256 + ot * 64) * 256;
  const float* bias = bvec + mat * 256 + ot * 64;
  float scale = mat ? 1.0f : 0.25505419776f;   // (1/sqrt(32)) * log2(e) for Q

  int tid = threadIdx.x;
  int lane = tid & 63, wave = tid >> 6;
  int lo = lane & 15, hi = lane >> 4;

  float bl[4];
  #pragma unroll
  for (int r = 0; r < 4; r++) bl[r] = bias[wave * 16 + hi * 4 + r];

  f32x4 acc[25];
  #pragma unroll
  for (int t = 0; t < 25; t++) acc[t] = (f32x4){0.f, 0.f, 0.f, 0.f};

  for (int e0 = 0; e0 < 256; e0 += 32){
    __syncthreads();
    // stage W tile: 64 rows x 32 e (fp32 -> bf16)
    for (int c = tid; c < 512; c += 256){
      int row = c >> 3, e4 = c & 7;
      float4 w4 = *(const float4*)(Wrow + row * 256 + e0 + e4 * 4);
      ushort4 pk;
      pk.x = f2bf(w4.x); pk.y = f2bf(w4.y); pk.z = f2bf(w4.z); pk.w = f2bf(w4.w);
      int idx = row * 32 + ((e4 * 4) ^ ((row & 3) << 3));
      *(ushort4*)(lds_a + idx) = pk;
    }
    // stage F tile: 32 e-rows x 400 s, transposed into [s][e] with swizzle
    for (int c = tid; c < 1600; c += 256){
      int er = c & 31, s8 = c >> 5;
      u16x8 v = *(const u16x8*)(F + ((n * 256 + e0 + er) * 400 + s8 * 8));
      #pragma unroll
      for (int j = 0; j < 8; j++){
        int s = s8 * 8 + j;
        lds_b[s * 32 + (er ^ ((s & 3) << 3))] = v[j];
      }
    }
    __syncthreads();
    // compute: A-frag for this wave's 16 o rows, 25 s-tiles
    bf16x8 afr = *(const bf16x8*)(lds_a + (wave * 16 + lo) * 32 + ((hi * 8) ^ ((lo & 3) << 3)));
    #pragma unroll
    for (int st = 0; st < 25; st++){
      bf16x8 bfr = *(const bf16x8*)(lds_b + (st * 16 + lo) * 32 + ((hi * 8) ^ ((lo & 3) << 3)));
      acc[st] = __builtin_amdgcn_mfma_f32_16x16x32_bf16(afr, bfr, acc[st], 0, 0, 0);
    }
  }
  // epilogue: o_local = wave*16 + hi*4 + r; 4 consecutive d -> one b64 store
  int o_loc = wave * 16 + hi * 4;
  int hh = ot * 2 + (o_loc >> 5);
  int d0 = o_loc & 31;
  #pragma unroll
  for (int st = 0; st < 25; st++){
    int s = st * 16 + lo;
    ushort4 pk;
    pk.x = f2bf((acc[st][0] + bl[0]) * scale);
    pk.y = f2bf((acc[st][1] + bl[1]) * scale);
    pk.z = f2bf((acc[st][2] + bl[2]) * scale);
    pk.w = f2bf((acc[st][3] + bl[3]) * scale);
    *(ushort4*)(O + ((size_t)((n * 8 + hh) * 400 + s)) * 32 + d0) = pk;
  }
}

// ---------- 4) fused scores+softmax+colsum: s-SPLIT across waves ----------
// colsum[n][h][s] = sum_l exp2(S[l,s]) * invz[l]   (Q pre-scaled by log2e; no max:
// scores O(+-10), exp2 overflow needs |score|>120)
// Wave w owns s-tiles st = w+4j (j<7): K frags (28 VGPR) live in registers for
// both passes; csacc is only 28 VGPR. l-range split across 2 blocks (grid .y)
// for occupancy; partial colsums summed in imp_kernel. No spill, no K LDS.
__global__ __launch_bounds__(256) void attn_kernel(const u16* __restrict__ qp,
                                                   const u16* __restrict__ kp,
                                                   float* __restrict__ colsum2){
  __shared__ float zp[4 * 208];     // per-wave z partials [w][li*16+lo]
  __shared__ float invzl[208];

  int bx = blockIdx.x;              // (n,h)
  int yhalf = blockIdx.y;           // l-range half
  int lt0 = yhalf ? 13 : 0;
  int nl  = yhalf ? 12 : 13;
  int tid = threadIdx.x;
  int lane = tid & 63, w = tid >> 6;
  int lo = lane & 15, hi = lane >> 4;

  const u16* qb = qp + (size_t)bx * 400 * 32;
  const u16* kb = kp + (size_t)bx * 400 * 32;

  // K fragments in registers: st = w + 4*j
  bf16x8 kfr[7];
  #pragma unroll
  for (int j = 0; j < 7; j++){
    int st = w + 4 * j;
    if (st < 25) kfr[j] = *(const bf16x8*)(kb + (st * 16 + lo) * 32 + hi * 8);
  }

  // ---- pass A: per-l denominator partials over this wave's s range ----
  for (int li = 0; li < nl; li++){
    int lt = lt0 + li;
    bf16x8 qfr = *(const bf16x8*)(qb + (lt * 16 + lo) * 32 + hi * 8);
    float z = 0.f;
    #pragma unroll
    for (int j = 0; j < 7; j++){
      int st = w + 4 * j;
      if (st < 25){
        f32x4 sc = __builtin_amdgcn_mfma_f32_16x16x32_bf16(kfr[j], qfr, (f32x4){0.f,0.f,0.f,0.f}, 0, 0, 0);
        z += (exp2f(sc[0]) + exp2f(sc[1])) + (exp2f(sc[2]) + exp2f(sc[3]));
      }
    }
    z += __shfl_xor(z, 16, 64);
    z += __shfl_xor(z, 32, 64);
    if (hi == 0) zp[w * 208 + li * 16 + lo] = z;
  }
  __syncthreads();
  for (int i = tid; i < nl * 16; i += 256)
    invzl[i] = 1.0f / (((zp[i] + zp[208 + i]) + (zp[416 + i] + zp[624 + i])));
  __syncthreads();

  // ---- pass B: recompute scores, accumulate weighted colsum partials ----
  float csacc[7][4];
  #pragma unroll
  for (int j = 0; j < 7; j++){
    #pragma unroll
    for (int r = 0; r < 4; r++) csacc[j][r] = 0.f;
  }
  for (int li = 0; li < nl; li++){
    int lt = lt0 + li;
    bf16x8 qfr = *(const bf16x8*)(qb + (lt * 16 + lo) * 32 + hi * 8);
    float wl = invzl[li * 16 + lo];
    #pragma unroll
    for (int j = 0; j < 7; j++){
      int st = w + 4 * j;
      if (st < 25){
        f32x4 sc = __builtin_amdgcn_mfma_f32_16x16x32_bf16(kfr[j], qfr, (f32x4){0.f,0.f,0.f,0.f}, 0, 0, 0);
        csacc[j][0] += exp2f(sc[0]) * wl;
        csacc[j][1] += exp2f(sc[1]) * wl;
        csacc[j][2] += exp2f(sc[2]) * wl;
        csacc[j][3] += exp2f(sc[3]) * wl;
      }
    }
  }

  // reduce over the 16 l-lanes (lo) and write partial colsum
  #pragma unroll
  for (int j = 0; j < 7; j++){
    int st = w + 4 * j;
    if (st < 25){
      #pragma unroll
      for (int r = 0; r < 4; r++){
        float v = csacc[j][r];
        v += __shfl_xor(v, 1, 64);
        v += __shfl_xor(v, 2, 64);
        v += __shfl_xor(v, 4, 64);
        v += __shfl_xor(v, 8, 64);
        if (lo == 0)
          colsum2[((size_t)(yhalf * 512 + bx)) * 400 + st * 16 + hi * 4 + r] = v;
      }
    }
  }
}

// ---------- 5) importance: imp[n][s] = sigmoid(sal_w * mean + sal_b) ----------
__global__ __launch_bounds__(256) void imp_kernel(const float* __restrict__ colsum2,
                                                  const float* __restrict__ sal_w,
                                                  const float* __restrict__ sal_b,
                                                  float* __restrict__ imp){
  int idx = blockIdx.x * 256 + threadIdx.x;   // [0, 25600)
  int n = idx / 400, s = idx - n * 400;
  float sum = 0.f;
  #pragma unroll
  for (int h = 0; h < 8; h++){
    sum += colsum2[(size_t)(n * 8 + h) * 400 + s];
    sum += colsum2[(size_t)(512 + n * 8 + h) * 400 + s];
  }
  float aw = sum * (1.0f / 3200.0f);
  float zz = sal_w[0] * aw + sal_b[0];
  imp[idx] = 1.0f / (1.0f + __expf(-zz));
}

// ---------- 6) final merge: out[e][Y][X] = loc*0.6*imp + 0.5*up_glb ----------
__global__ __launch_bounds__(256) void out_kernel(const float* __restrict__ xin,
                                                  const float* __restrict__ imp,
                                                  float* __restrict__ out){
  int flat = blockIdx.x * 256 + threadIdx.x;  // [0, 256*160*40)
  int x4 = flat % 40;
  int rest = flat / 40;
  int Y = rest % 160;
  int e = rest / 160;
  int X0 = x4 * 4;
  int a = (Y >= 80) ? 1 : 0;
  int bq = (X0 >= 80) ? 1 : 0;
  int yy = Y - a * 80, xx = X0 - bq * 80;
  int pi = yy / 20, y = yy - pi * 20;
  int pj = xx / 20, x0 = xx - pj * 20;
  int img = a * 2 + bq;
  int nn = img * 16 + pi * 4 + pj;
  int s0 = y * 20 + x0;
  float4 l4 = *(const float4*)(xin + ((img * 256 + e) * 80 + yy) * 80 + xx);
  float4 i4 = *(const float4*)(imp + nn * 400 + s0);
  const float* g = xin + (4 * 256 + e) * 6400;
  float4 u4 = up4(g, Y, X0);
  float4 o;
  o.x = l4.x * (0.6f * i4.x) + 0.5f * u4.x;
  o.y = l4.y * (0.6f * i4.y) + 0.5f * u4.y;
  o.z = l4.z * (0.6f * i4.z) + 0.5f * u4.z;
  o.w = l4.w * (0.6f * i4.w) + 0.5f * u4.w;
  *(float4*)(out + (e * 160 + Y) * 160 + X0) = o;
}

// ---------- launch ----------
extern "C" void kernel_launch(void* const* d_in, const int* in_sizes, int n_in,
                              void* d_out, int out_size, void* d_ws, size_t ws_size,
                              hipStream_t stream) {
  const float* x      = (const float*)d_in[0];   // [5,256,80,80]
  const float* W      = (const float*)d_in[1];   // [768,256]
  const float* bvec   = (const float*)d_in[2];   // [768]
  const float* sal_w  = (const float*)d_in[3];
  const float* sal_b  = (const float*)d_in[4];
  float* out = (float*)d_out;                    // [256,160,160]

  // ws layout (all offsets 16B-aligned)
  const size_t POS_OFF = 0;                         // 256*400*4      =   409600
  const size_t QF_OFF  = 409600;                    // 64*256*400*2   = 13107200
  const size_t KF_OFF  = QF_OFF + 13107200;
  const size_t QP_OFF  = KF_OFF + 13107200;
  const size_t KP_OFF  = QP_OFF + 13107200;
  const size_t CS_OFF  = KP_OFF + 13107200;         // 2*512*400*4    =  1638400
  const size_t IMP_OFF = CS_OFF + 1638400;          // 64*400*4       =   102400
  const size_t NEED    = IMP_OFF + 102400;          // 54,579,200 B
  if (ws_size < NEED) return;   // insufficient scratch: leave output poisoned (clean fail)

  char* ws = (char*)d_ws;
  float* pos    = (float*)(ws + POS_OFF);
  u16*   qf     = (u16*)(ws + QF_OFF);
  u16*   kf     = (u16*)(ws + KF_OFF);
  u16*   qp     = (u16*)(ws + QP_OFF);
  u16*   kp     = (u16*)(ws + KP_OFF);
  float* colsum2= (float*)(ws + CS_OFF);
  float* imp    = (float*)(ws + IMP_OFF);

  pos_kernel<<<400, 256, 0, stream>>>(pos);
  feat_kernel<<<dim3(6400, 2), 256, 0, stream>>>(x, pos, qf, kf);
  proj_kernel<<<dim3(256, 2), 256, 0, stream>>>(qf, kf, W, bvec, qp, kp);
  attn_kernel<<<dim3(512, 2), 256, 0, stream>>>(qp, kp, colsum2);
  imp_kernel<<<100, 256, 0, stream>>>(colsum2, sal_w, sal_b, imp);
  out_kernel<<<6400, 256, 0, stream>>>(x, imp, out);
}

// Round 6
// 112.086 us; speedup vs baseline: 1.3178x; 1.1142x over previous
//
#include <hip/hip_runtime.h>
#include <math.h>

typedef __attribute__((ext_vector_type(8))) short bf16x8;           // MFMA A/B frag (8 bf16)
typedef __attribute__((ext_vector_type(8))) unsigned short u16x8;   // 16B bf16 load
typedef __attribute__((ext_vector_type(4))) float f32x4;            // MFMA C/D frag
typedef unsigned short u16;

// ---------- constants ----------
// x: [5,256,80,80] f32; loc = x[:4], glb = x[4]
// patches: 64 of [256,20,20]; S = 400; heads = 8; d = 32

__device__ __forceinline__ u16 f2bf(float f){
  unsigned u = __float_as_uint(f);
  u += 0x7fffu + ((u >> 16) & 1u);           // RNE
  return (u16)(u >> 16);
}

// bilinear 2x upsample (jax half-pixel, edge-renormalized == clamp) of an
// 80x80 plane at output row Y, cols X0..X0+3 (X0 even).
__device__ __forceinline__ float4 up4(const float* __restrict__ g, int Y, int X0){
  int jy = Y >> 1;
  int ry0, ry1; float wy0, wy1;
  if (Y & 1){ ry0 = jy; ry1 = (jy < 79) ? jy + 1 : 79; wy0 = 0.75f; wy1 = 0.25f; }
  else      { ry0 = (jy > 0) ? jy - 1 : 0; ry1 = jy;   wy0 = 0.25f; wy1 = 0.75f; }
  int jx = X0 >> 1;
  int cm1 = (jx > 0) ? jx - 1 : 0;
  int cp2 = (jx < 78) ? jx + 2 : 79;
  const float* r0 = g + ry0 * 80;
  const float* r1 = g + ry1 * 80;
  float cvm = wy0 * r0[cm1]  + wy1 * r1[cm1];
  float cv0 = wy0 * r0[jx]   + wy1 * r1[jx];
  float cv1 = wy0 * r0[jx+1] + wy1 * r1[jx+1];
  float cv2 = wy0 * r0[cp2]  + wy1 * r1[cp2];
  return make_float4(0.25f*cvm + 0.75f*cv0,
                     0.75f*cv0 + 0.25f*cv1,
                     0.25f*cv0 + 0.75f*cv1,
                     0.75f*cv1 + 0.25f*cv2);
}

// ---------- 1) positional embedding table: pos[e][s], [256][400] f32 ----------
__global__ __launch_bounds__(256) void pos_kernel(float* __restrict__ pos){
  int idx = blockIdx.x * 256 + threadIdx.x;      // [0, 102400)
  int e = idx / 400, s = idx - e * 400;
  int y = s / 20, x = s - y * 20;
  int j = e & 127;
  int m = j >> 1;
  int k = (e < 128) ? y : x;
  float v = ((float)k + 0.5f) * (6.2831853071795864769f / 20.000001f);
  float invT = exp2f(-(float)m * 0.20762050593049448f);   // 10000^(-m/64)
  float arg = v * invT;
  pos[idx] = (j & 1) ? cosf(arg) : sinf(arg);
}

// ---------- 2) feature build: Qf/Kf [n][e][s] bf16 (channel-major) ----------
__global__ __launch_bounds__(256) void feat_kernel(const float* __restrict__ xin,
                                                   const float* __restrict__ pos,
                                                   u16* __restrict__ qf,
                                                   u16* __restrict__ kf){
  int which = blockIdx.y;                         // 0: query(loc), 1: key(upsampled glb)
  int flat = blockIdx.x * 256 + threadIdx.x;      // [0, 64*256*100)
  int s4 = flat % 100;
  int rest = flat / 100;
  int e = rest & 255;
  int n = rest >> 8;
  int s0 = s4 * 4;
  int y = s0 / 20, x0 = s0 - y * 20;              // 4 consecutive x within one row
  float4 pv = *(const float4*)(pos + e * 400 + s0);
  float4 val;
  u16* dst;
  if (which == 0){
    int img = n >> 4, pi = (n >> 2) & 3, pj = n & 3;
    const float* src = xin + (((img * 256 + e) * 80) + (pi * 20 + y)) * 80 + (pj * 20 + x0);
    float4 l = *(const float4*)src;
    val.x = l.x + pv.x; val.y = l.y + pv.y; val.z = l.z + pv.z; val.w = l.w + pv.w;
    dst = qf;
  } else {
    int gi = n >> 3, gj = n & 7;
    const float* g = xin + (4 * 256 + e) * 6400;
    float4 u = up4(g, gi * 20 + y, gj * 20 + x0);
    val.x = u.x + pv.x; val.y = u.y + pv.y; val.z = u.z + pv.z; val.w = u.w + pv.w;
    dst = kf;
  }
  ushort4 o;
  o.x = f2bf(val.x); o.y = f2bf(val.y); o.z = f2bf(val.z); o.w = f2bf(val.w);
  *(ushort4*)(dst + ((n * 256 + e) * 400 + s0)) = o;
}

// ---------- 3) projection GEMM: C_n[o][s] = sum_e W[o][e]*F_n[e][s] ----------
// grid (n*4+ot, mat), 256 thr (4 waves), each wave: 16 o-rows x 400 s. K-loop e in steps of 32.
// Epilogue writes head-major layout: O[((n*8+h)*400 + s)*32 + d], h=o>>5, d=o&31.
// Q additionally scaled by (1/sqrt(32))*log2(e) so attention scores land in exp2 domain.
__global__ __launch_bounds__(256) void proj_kernel(const u16* __restrict__ qf,
                                                   const u16* __restrict__ kf,
                                                   const float* __restrict__ W,
                                                   const float* __restrict__ bvec,
                                                   u16* __restrict__ qp,
                                                   u16* __restrict__ kp){
  __shared__ u16 lds_a[64 * 32];    // W tile [o_local][e], XOR-swizzled rows of 64B
  __shared__ u16 lds_b[400 * 32];   // F tile [s][e], XOR-swizzled

  int mat = blockIdx.y;
  int bx = blockIdx.x;
  int n = bx >> 2, ot = bx & 3;
  const u16* F = mat ? kf : qf;
  u16* O = mat ? kp : qp;
  const float* Wrow = W + (mat * 256 + ot * 64) * 256;
  const float* bias = bvec + mat * 256 + ot * 64;
  float scale = mat ? 1.0f : 0.25505419776f;   // (1/sqrt(32)) * log2(e) for Q

  int tid = threadIdx.x;
  int lane = tid & 63, wave = tid >> 6;
  int lo = lane & 15, hi = lane >> 4;

  float bl[4];
  #pragma unroll
  for (int r = 0; r < 4; r++) bl[r] = bias[wave * 16 + hi * 4 + r];

  f32x4 acc[25];
  #pragma unroll
  for (int t = 0; t < 25; t++) acc[t] = (f32x4){0.f, 0.f, 0.f, 0.f};

  for (int e0 = 0; e0 < 256; e0 += 32){
    __syncthreads();
    // stage W tile: 64 rows x 32 e (fp32 -> bf16)
    for (int c = tid; c < 512; c += 256){
      int row = c >> 3, e4 = c & 7;
      float4 w4 = *(const float4*)(Wrow + row * 256 + e0 + e4 * 4);
      ushort4 pk;
      pk.x = f2bf(w4.x); pk.y = f2bf(w4.y); pk.z = f2bf(w4.z); pk.w = f2bf(w4.w);
      int idx = row * 32 + ((e4 * 4) ^ ((row & 3) << 3));
      *(ushort4*)(lds_a + idx) = pk;
    }
    // stage F tile: 32 e-rows x 400 s, transposed into [s][e] with swizzle
    for (int c = tid; c < 1600; c += 256){
      int er = c & 31, s8 = c >> 5;
      u16x8 v = *(const u16x8*)(F + ((n * 256 + e0 + er) * 400 + s8 * 8));
      #pragma unroll
      for (int j = 0; j < 8; j++){
        int s = s8 * 8 + j;
        lds_b[s * 32 + (er ^ ((s & 3) << 3))] = v[j];
      }
    }
    __syncthreads();
    // compute: A-frag for this wave's 16 o rows, 25 s-tiles
    bf16x8 afr = *(const bf16x8*)(lds_a + (wave * 16 + lo) * 32 + ((hi * 8) ^ ((lo & 3) << 3)));
    #pragma unroll
    for (int st = 0; st < 25; st++){
      bf16x8 bfr = *(const bf16x8*)(lds_b + (st * 16 + lo) * 32 + ((hi * 8) ^ ((lo & 3) << 3)));
      acc[st] = __builtin_amdgcn_mfma_f32_16x16x32_bf16(afr, bfr, acc[st], 0, 0, 0);
    }
  }
  // epilogue: o_local = wave*16 + hi*4 + r; 4 consecutive d -> one b64 store
  int o_loc = wave * 16 + hi * 4;
  int hh = ot * 2 + (o_loc >> 5);
  int d0 = o_loc & 31;
  #pragma unroll
  for (int st = 0; st < 25; st++){
    int s = st * 16 + lo;
    ushort4 pk;
    pk.x = f2bf((acc[st][0] + bl[0]) * scale);
    pk.y = f2bf((acc[st][1] + bl[1]) * scale);
    pk.z = f2bf((acc[st][2] + bl[2]) * scale);
    pk.w = f2bf((acc[st][3] + bl[3]) * scale);
    *(ushort4*)(O + ((size_t)((n * 8 + hh) * 400 + s)) * 32 + d0) = pk;
  }
}

// ---------- 4) fused scores+softmax+colsum: ONE-PASS, s-split across waves ----------
// colsum[n][h][s] = sum_l exp2(S[l,s]) * invz[l]   (Q pre-scaled by log2e; no max:
// scores O(+-10), exp2 overflow needs |score|>120)
// Wave w owns s-tiles st = w+4j (j<7): K frags (28 VGPR) in registers. Per l-iter:
// compute 28 exps (keep in 28 regs), exchange z-partials through double-buffered
// LDS (one barrier), then csacc += p*invz. Single pass over all scores.
// l-range split across 2 blocks (grid .y); partials summed in imp_kernel.
__global__ __launch_bounds__(256) void attn_kernel(const u16* __restrict__ qp,
                                                   const u16* __restrict__ kp,
                                                   float* __restrict__ colsum2){
  __shared__ float zp[2][4][16];    // [parity][wave][lo] z partials

  int bx = blockIdx.x;              // (n,h)
  int yhalf = blockIdx.y;           // l-range half
  int lt0 = yhalf ? 13 : 0;
  int nl  = yhalf ? 12 : 13;
  int tid = threadIdx.x;
  int lane = tid & 63, w = tid >> 6;
  int lo = lane & 15, hi = lane >> 4;

  const u16* qb = qp + (size_t)bx * 400 * 32;
  const u16* kb = kp + (size_t)bx * 400 * 32;

  // K fragments in registers: st = w + 4*j
  bf16x8 kfr[7];
  #pragma unroll
  for (int j = 0; j < 7; j++){
    int st = w + 4 * j;
    if (st < 25) kfr[j] = *(const bf16x8*)(kb + (st * 16 + lo) * 32 + hi * 8);
  }

  float csacc[7][4];
  #pragma unroll
  for (int j = 0; j < 7; j++){
    #pragma unroll
    for (int r = 0; r < 4; r++) csacc[j][r] = 0.f;
  }

  for (int li = 0; li < nl; li++){
    int lt = lt0 + li;
    bf16x8 qfr = *(const bf16x8*)(qb + (lt * 16 + lo) * 32 + hi * 8);
    f32x4 p[7];
    float z = 0.f;
    #pragma unroll
    for (int j = 0; j < 7; j++){
      int st = w + 4 * j;
      if (st < 25){
        f32x4 sc = __builtin_amdgcn_mfma_f32_16x16x32_bf16(kfr[j], qfr, (f32x4){0.f,0.f,0.f,0.f}, 0, 0, 0);
        p[j][0] = exp2f(sc[0]);
        p[j][1] = exp2f(sc[1]);
        p[j][2] = exp2f(sc[2]);
        p[j][3] = exp2f(sc[3]);
        z += (p[j][0] + p[j][1]) + (p[j][2] + p[j][3]);
      }
    }
    // z partial for q-row l=lt*16+lo: reduce over hi lanes, exchange across waves
    z += __shfl_xor(z, 16, 64);
    z += __shfl_xor(z, 32, 64);
    int par = li & 1;
    if (hi == 0) zp[par][w][lo] = z;
    __syncthreads();
    float invz = 1.0f / ((zp[par][0][lo] + zp[par][1][lo]) + (zp[par][2][lo] + zp[par][3][lo]));
    #pragma unroll
    for (int j = 0; j < 7; j++){
      if (w + 4 * j < 25){
        csacc[j][0] += p[j][0] * invz;
        csacc[j][1] += p[j][1] * invz;
        csacc[j][2] += p[j][2] * invz;
        csacc[j][3] += p[j][3] * invz;
      }
    }
  }

  // reduce over the 16 l-lanes (lo) and write partial colsum
  #pragma unroll
  for (int j = 0; j < 7; j++){
    int st = w + 4 * j;
    if (st < 25){
      #pragma unroll
      for (int r = 0; r < 4; r++){
        float v = csacc[j][r];
        v += __shfl_xor(v, 1, 64);
        v += __shfl_xor(v, 2, 64);
        v += __shfl_xor(v, 4, 64);
        v += __shfl_xor(v, 8, 64);
        if (lo == 0)
          colsum2[((size_t)(yhalf * 512 + bx)) * 400 + st * 16 + hi * 4 + r] = v;
      }
    }
  }
}

// ---------- 5) importance: imp[n][s] = sigmoid(sal_w * mean + sal_b) ----------
__global__ __launch_bounds__(256) void imp_kernel(const float* __restrict__ colsum2,
                                                  const float* __restrict__ sal_w,
                                                  const float* __restrict__ sal_b,
                                                  float* __restrict__ imp){
  int idx = blockIdx.x * 256 + threadIdx.x;   // [0, 25600)
  int n = idx / 400, s = idx - n * 400;
  float sum = 0.f;
  #pragma unroll
  for (int h = 0; h < 8; h++){
    sum += colsum2[(size_t)(n * 8 + h) * 400 + s];
    sum += colsum2[(size_t)(512 + n * 8 + h) * 400 + s];
  }
  float aw = sum * (1.0f / 3200.0f);
  float zz = sal_w[0] * aw + sal_b[0];
  imp[idx] = 1.0f / (1.0f + __expf(-zz));
}

// ---------- 6) final merge: out[e][Y][X] = loc*0.6*imp + 0.5*up_glb ----------
__global__ __launch_bounds__(256) void out_kernel(const float* __restrict__ xin,
                                                  const float* __restrict__ imp,
                                                  float* __restrict__ out){
  int flat = blockIdx.x * 256 + threadIdx.x;  // [0, 256*160*40)
  int x4 = flat % 40;
  int rest = flat / 40;
  int Y = rest % 160;
  int e = rest / 160;
  int X0 = x4 * 4;
  int a = (Y >= 80) ? 1 : 0;
  int bq = (X0 >= 80) ? 1 : 0;
  int yy = Y - a * 80, xx = X0 - bq * 80;
  int pi = yy / 20, y = yy - pi * 20;
  int pj = xx / 20, x0 = xx - pj * 20;
  int img = a * 2 + bq;
  int nn = img * 16 + pi * 4 + pj;
  int s0 = y * 20 + x0;
  float4 l4 = *(const float4*)(xin + ((img * 256 + e) * 80 + yy) * 80 + xx);
  float4 i4 = *(const float4*)(imp + nn * 400 + s0);
  const float* g = xin + (4 * 256 + e) * 6400;
  float4 u4 = up4(g, Y, X0);
  float4 o;
  o.x = l4.x * (0.6f * i4.x) + 0.5f * u4.x;
  o.y = l4.y * (0.6f * i4.y) + 0.5f * u4.y;
  o.z = l4.z * (0.6f * i4.z) + 0.5f * u4.z;
  o.w = l4.w * (0.6f * i4.w) + 0.5f * u4.w;
  *(float4*)(out + (e * 160 + Y) * 160 + X0) = o;
}

// ---------- launch ----------
extern "C" void kernel_launch(void* const* d_in, const int* in_sizes, int n_in,
                              void* d_out, int out_size, void* d_ws, size_t ws_size,
                              hipStream_t stream) {
  const float* x      = (const float*)d_in[0];   // [5,256,80,80]
  const float* W      = (const float*)d_in[1];   // [768,256]
  const float* bvec   = (const float*)d_in[2];   // [768]
  const float* sal_w  = (const float*)d_in[3];
  const float* sal_b  = (const float*)d_in[4];
  float* out = (float*)d_out;                    // [256,160,160]

  // ws layout (all offsets 16B-aligned)
  const size_t POS_OFF = 0;                         // 256*400*4      =   409600
  const size_t QF_OFF  = 409600;                    // 64*256*400*2   = 13107200
  const size_t KF_OFF  = QF_OFF + 13107200;
  const size_t QP_OFF  = KF_OFF + 13107200;
  const size_t KP_OFF  = QP_OFF + 13107200;
  const size_t CS_OFF  = KP_OFF + 13107200;         // 2*512*400*4    =  1638400
  const size_t IMP_OFF = CS_OFF + 1638400;          // 64*400*4       =   102400
  const size_t NEED    = IMP_OFF + 102400;          // 54,579,200 B
  if (ws_size < NEED) return;   // insufficient scratch: leave output poisoned (clean fail)

  char* ws = (char*)d_ws;
  float* pos    = (float*)(ws + POS_OFF);
  u16*   qf     = (u16*)(ws + QF_OFF);
  u16*   kf     = (u16*)(ws + KF_OFF);
  u16*   qp     = (u16*)(ws + QP_OFF);
  u16*   kp     = (u16*)(ws + KP_OFF);
  float* colsum2= (float*)(ws + CS_OFF);
  float* imp    = (float*)(ws + IMP_OFF);

  pos_kernel<<<400, 256, 0, stream>>>(pos);
  feat_kernel<<<dim3(6400, 2), 256, 0, stream>>>(x, pos, qf, kf);
  proj_kernel<<<dim3(256, 2), 256, 0, stream>>>(qf, kf, W, bvec, qp, kp);
  attn_kernel<<<dim3(512, 2), 256, 0, stream>>>(qp, kp, colsum2);
  imp_kernel<<<100, 256, 0, stream>>>(colsum2, sal_w, sal_b, imp);
  out_kernel<<<6400, 256, 0, stream>>>(x, imp, out);
}

// Round 7
// 111.080 us; speedup vs baseline: 1.3297x; 1.0091x over previous
//
#include <hip/hip_runtime.h>
#include <math.h>

typedef __attribute__((ext_vector_type(8))) short bf16x8;           // MFMA A/B frag (8 bf16)
typedef __attribute__((ext_vector_type(8))) unsigned short u16x8;   // 16B bf16 load
typedef __attribute__((ext_vector_type(4))) float f32x4;            // MFMA C/D frag
typedef unsigned short u16;

// ---------- constants ----------
// x: [5,256,80,80] f32; loc = x[:4], glb = x[4]
// patches: 64 of [256,20,20]; S = 400; heads = 8; d = 32

__device__ __forceinline__ u16 f2bf(float f){
  unsigned u = __float_as_uint(f);
  u += 0x7fffu + ((u >> 16) & 1u);           // RNE
  return (u16)(u >> 16);
}

// bilinear 2x upsample (jax half-pixel, edge-renormalized == clamp) of an
// 80x80 plane at output row Y, cols X0..X0+3 (X0 even).
__device__ __forceinline__ float4 up4(const float* __restrict__ g, int Y, int X0){
  int jy = Y >> 1;
  int ry0, ry1; float wy0, wy1;
  if (Y & 1){ ry0 = jy; ry1 = (jy < 79) ? jy + 1 : 79; wy0 = 0.75f; wy1 = 0.25f; }
  else      { ry0 = (jy > 0) ? jy - 1 : 0; ry1 = jy;   wy0 = 0.25f; wy1 = 0.75f; }
  int jx = X0 >> 1;
  int cm1 = (jx > 0) ? jx - 1 : 0;
  int cp2 = (jx < 78) ? jx + 2 : 79;
  const float* r0 = g + ry0 * 80;
  const float* r1 = g + ry1 * 80;
  float cvm = wy0 * r0[cm1]  + wy1 * r1[cm1];
  float cv0 = wy0 * r0[jx]   + wy1 * r1[jx];
  float cv1 = wy0 * r0[jx+1] + wy1 * r1[jx+1];
  float cv2 = wy0 * r0[cp2]  + wy1 * r1[cp2];
  return make_float4(0.25f*cvm + 0.75f*cv0,
                     0.75f*cv0 + 0.25f*cv1,
                     0.25f*cv0 + 0.75f*cv1,
                     0.75f*cv1 + 0.25f*cv2);
}

// ---------- 1) positional embedding table: pos[e][s], [256][400] f32 ----------
__global__ __launch_bounds__(256) void pos_kernel(float* __restrict__ pos){
  int idx = blockIdx.x * 256 + threadIdx.x;      // [0, 102400)
  int e = idx / 400, s = idx - e * 400;
  int y = s / 20, x = s - y * 20;
  int j = e & 127;
  int m = j >> 1;
  int k = (e < 128) ? y : x;
  float v = ((float)k + 0.5f) * (6.2831853071795864769f / 20.000001f);
  float invT = exp2f(-(float)m * 0.20762050593049448f);   // 10000^(-m/64)
  float arg = v * invT;
  pos[idx] = (j & 1) ? cosf(arg) : sinf(arg);
}

// ---------- 2) feature build: Qf/Kf [n][e][s] bf16 (channel-major) ----------
__global__ __launch_bounds__(256) void feat_kernel(const float* __restrict__ xin,
                                                   const float* __restrict__ pos,
                                                   u16* __restrict__ qf,
                                                   u16* __restrict__ kf){
  int which = blockIdx.y;                         // 0: query(loc), 1: key(upsampled glb)
  int flat = blockIdx.x * 256 + threadIdx.x;      // [0, 64*256*100)
  int s4 = flat % 100;
  int rest = flat / 100;
  int e = rest & 255;
  int n = rest >> 8;
  int s0 = s4 * 4;
  int y = s0 / 20, x0 = s0 - y * 20;              // 4 consecutive x within one row
  float4 pv = *(const float4*)(pos + e * 400 + s0);
  float4 val;
  u16* dst;
  if (which == 0){
    int img = n >> 4, pi = (n >> 2) & 3, pj = n & 3;
    const float* src = xin + (((img * 256 + e) * 80) + (pi * 20 + y)) * 80 + (pj * 20 + x0);
    float4 l = *(const float4*)src;
    val.x = l.x + pv.x; val.y = l.y + pv.y; val.z = l.z + pv.z; val.w = l.w + pv.w;
    dst = qf;
  } else {
    int gi = n >> 3, gj = n & 7;
    const float* g = xin + (4 * 256 + e) * 6400;
    float4 u = up4(g, gi * 20 + y, gj * 20 + x0);
    val.x = u.x + pv.x; val.y = u.y + pv.y; val.z = u.z + pv.z; val.w = u.w + pv.w;
    dst = kf;
  }
  ushort4 o;
  o.x = f2bf(val.x); o.y = f2bf(val.y); o.z = f2bf(val.z); o.w = f2bf(val.w);
  *(ushort4*)(dst + ((n * 256 + e) * 400 + s0)) = o;
}

// ---------- 3) projection GEMM: C_n[o][s] = sum_e W[o][e]*F_n[e][s] ----------
// grid (n*4+ot, mat), 256 thr (4 waves), each wave: 16 o-rows x 400 s. K-loop e in steps of 32.
// Epilogue writes head-major layout: O[((n*8+h)*400 + s)*32 + d], h=o>>5, d=o&31.
// Q additionally scaled by (1/sqrt(32))*log2(e) so attention scores land in exp2 domain.
__global__ __launch_bounds__(256) void proj_kernel(const u16* __restrict__ qf,
                                                   const u16* __restrict__ kf,
                                                   const float* __restrict__ W,
                                                   const float* __restrict__ bvec,
                                                   u16* __restrict__ qp,
                                                   u16* __restrict__ kp){
  __shared__ u16 lds_a[64 * 32];    // W tile [o_local][e], XOR-swizzled rows of 64B
  __shared__ u16 lds_b[400 * 32];   // F tile [s][e], XOR-swizzled

  int mat = blockIdx.y;
  int bx = blockIdx.x;
  int n = bx >> 2, ot = bx & 3;
  const u16* F = mat ? kf : qf;
  u16* O = mat ? kp : qp;
  const float* Wrow = W + (mat * 256 + ot * 64) * 256;
  const float* bias = bvec + mat * 256 + ot * 64;
  float scale = mat ? 1.0f : 0.25505419776f;   // (1/sqrt(32)) * log2(e) for Q

  int tid = threadIdx.x;
  int lane = tid & 63, wave = tid >> 6;
  int lo = lane & 15, hi = lane >> 4;

  float bl[4];
  #pragma unroll
  for (int r = 0; r < 4; r++) bl[r] = bias[wave * 16 + hi * 4 + r];

  f32x4 acc[25];
  #pragma unroll
  for (int t = 0; t < 25; t++) acc[t] = (f32x4){0.f, 0.f, 0.f, 0.f};

  for (int e0 = 0; e0 < 256; e0 += 32){
    __syncthreads();
    // stage W tile: 64 rows x 32 e (fp32 -> bf16)
    for (int c = tid; c < 512; c += 256){
      int row = c >> 3, e4 = c & 7;
      float4 w4 = *(const float4*)(Wrow + row * 256 + e0 + e4 * 4);
      ushort4 pk;
      pk.x = f2bf(w4.x); pk.y = f2bf(w4.y); pk.z = f2bf(w4.z); pk.w = f2bf(w4.w);
      int idx = row * 32 + ((e4 * 4) ^ ((row & 3) << 3));
      *(ushort4*)(lds_a + idx) = pk;
    }
    // stage F tile: 32 e-rows x 400 s, transposed into [s][e] with swizzle
    for (int c = tid; c < 1600; c += 256){
      int er = c & 31, s8 = c >> 5;
      u16x8 v = *(const u16x8*)(F + ((n * 256 + e0 + er) * 400 + s8 * 8));
      #pragma unroll
      for (int j = 0; j < 8; j++){
        int s = s8 * 8 + j;
        lds_b[s * 32 + (er ^ ((s & 3) << 3))] = v[j];
      }
    }
    __syncthreads();
    // compute: A-frag for this wave's 16 o rows, 25 s-tiles
    bf16x8 afr = *(const bf16x8*)(lds_a + (wave * 16 + lo) * 32 + ((hi * 8) ^ ((lo & 3) << 3)));
    #pragma unroll
    for (int st = 0; st < 25; st++){
      bf16x8 bfr = *(const bf16x8*)(lds_b + (st * 16 + lo) * 32 + ((hi * 8) ^ ((lo & 3) << 3)));
      acc[st] = __builtin_amdgcn_mfma_f32_16x16x32_bf16(afr, bfr, acc[st], 0, 0, 0);
    }
  }
  // epilogue: o_local = wave*16 + hi*4 + r; 4 consecutive d -> one b64 store
  int o_loc = wave * 16 + hi * 4;
  int hh = ot * 2 + (o_loc >> 5);
  int d0 = o_loc & 31;
  #pragma unroll
  for (int st = 0; st < 25; st++){
    int s = st * 16 + lo;
    ushort4 pk;
    pk.x = f2bf((acc[st][0] + bl[0]) * scale);
    pk.y = f2bf((acc[st][1] + bl[1]) * scale);
    pk.z = f2bf((acc[st][2] + bl[2]) * scale);
    pk.w = f2bf((acc[st][3] + bl[3]) * scale);
    *(ushort4*)(O + ((size_t)((n * 8 + hh) * 400 + s)) * 32 + d0) = pk;
  }
}

// ---------- 4) fused scores+softmax+colsum: ONE-PASS, s-split across waves ----------
// colsum[n][h][s] = sum_l exp2(S[l,s]) * invz[l]   (Q pre-scaled by log2e; no max:
// scores O(+-10), exp2 overflow needs |score|>120)
// Wave w owns s-tiles st = w+4j (j<7): K frags (28 VGPR) in registers. Per l-iter:
// compute 28 exps (keep in 28 regs), exchange z-partials through double-buffered
// LDS (one barrier), then csacc += p*invz. Single pass over all scores.
// l-range split across 2 blocks (grid .y); partials summed in imp_kernel.
// __launch_bounds__(256,2): VGPR budget 128 so kfr/p/csacc (~90 regs) stay in
// architectural VGPRs -- without this the compiler caps at ~60 VGPR for occupancy
// and shuffles p/csacc through AGPRs with v_accvgpr_read/write on every access
// (R6: VALUBusy-time 7x the algorithmic VALU work).
__global__ __launch_bounds__(256, 2) void attn_kernel(const u16* __restrict__ qp,
                                                      const u16* __restrict__ kp,
                                                      float* __restrict__ colsum2){
  __shared__ float zp[2][4][16];    // [parity][wave][lo] z partials

  int bx = blockIdx.x;              // (n,h)
  int yhalf = blockIdx.y;           // l-range half
  int lt0 = yhalf ? 13 : 0;
  int nl  = yhalf ? 12 : 13;
  int tid = threadIdx.x;
  int lane = tid & 63, w = tid >> 6;
  int lo = lane & 15, hi = lane >> 4;

  const u16* qb = qp + (size_t)bx * 400 * 32;
  const u16* kb = kp + (size_t)bx * 400 * 32;

  // K fragments in registers: st = w + 4*j
  bf16x8 kfr[7];
  #pragma unroll
  for (int j = 0; j < 7; j++){
    int st = w + 4 * j;
    if (st < 25) kfr[j] = *(const bf16x8*)(kb + (st * 16 + lo) * 32 + hi * 8);
  }

  float csacc[7][4];
  #pragma unroll
  for (int j = 0; j < 7; j++){
    #pragma unroll
    for (int r = 0; r < 4; r++) csacc[j][r] = 0.f;
  }

  for (int li = 0; li < nl; li++){
    int lt = lt0 + li;
    bf16x8 qfr = *(const bf16x8*)(qb + (lt * 16 + lo) * 32 + hi * 8);
    f32x4 p[7];
    float z = 0.f;
    #pragma unroll
    for (int j = 0; j < 7; j++){
      int st = w + 4 * j;
      if (st < 25){
        f32x4 sc = __builtin_amdgcn_mfma_f32_16x16x32_bf16(kfr[j], qfr, (f32x4){0.f,0.f,0.f,0.f}, 0, 0, 0);
        p[j][0] = exp2f(sc[0]);
        p[j][1] = exp2f(sc[1]);
        p[j][2] = exp2f(sc[2]);
        p[j][3] = exp2f(sc[3]);
        z += (p[j][0] + p[j][1]) + (p[j][2] + p[j][3]);
      }
    }
    // z partial for q-row l=lt*16+lo: reduce over hi lanes, exchange across waves
    z += __shfl_xor(z, 16, 64);
    z += __shfl_xor(z, 32, 64);
    int par = li & 1;
    if (hi == 0) zp[par][w][lo] = z;
    __syncthreads();
    float invz = 1.0f / ((zp[par][0][lo] + zp[par][1][lo]) + (zp[par][2][lo] + zp[par][3][lo]));
    #pragma unroll
    for (int j = 0; j < 7; j++){
      if (w + 4 * j < 25){
        csacc[j][0] += p[j][0] * invz;
        csacc[j][1] += p[j][1] * invz;
        csacc[j][2] += p[j][2] * invz;
        csacc[j][3] += p[j][3] * invz;
      }
    }
  }

  // reduce over the 16 l-lanes (lo) and write partial colsum
  #pragma unroll
  for (int j = 0; j < 7; j++){
    int st = w + 4 * j;
    if (st < 25){
      #pragma unroll
      for (int r = 0; r < 4; r++){
        float v = csacc[j][r];
        v += __shfl_xor(v, 1, 64);
        v += __shfl_xor(v, 2, 64);
        v += __shfl_xor(v, 4, 64);
        v += __shfl_xor(v, 8, 64);
        if (lo == 0)
          colsum2[((size_t)(yhalf * 512 + bx)) * 400 + st * 16 + hi * 4 + r] = v;
      }
    }
  }
}

// ---------- 5) importance: imp[n][s] = sigmoid(sal_w * mean + sal_b) ----------
__global__ __launch_bounds__(256) void imp_kernel(const float* __restrict__ colsum2,
                                                  const float* __restrict__ sal_w,
                                                  const float* __restrict__ sal_b,
                                                  float* __restrict__ imp){
  int idx = blockIdx.x * 256 + threadIdx.x;   // [0, 25600)
  int n = idx / 400, s = idx - n * 400;
  float sum = 0.f;
  #pragma unroll
  for (int h = 0; h < 8; h++){
    sum += colsum2[(size_t)(n * 8 + h) * 400 + s];
    sum += colsum2[(size_t)(512 + n * 8 + h) * 400 + s];
  }
  float aw = sum * (1.0f / 3200.0f);
  float zz = sal_w[0] * aw + sal_b[0];
  imp[idx] = 1.0f / (1.0f + __expf(-zz));
}

// ---------- 6) final merge: out[e][Y][X] = loc*0.6*imp + 0.5*up_glb ----------
__global__ __launch_bounds__(256) void out_kernel(const float* __restrict__ xin,
                                                  const float* __restrict__ imp,
                                                  float* __restrict__ out){
  int flat = blockIdx.x * 256 + threadIdx.x;  // [0, 256*160*40)
  int x4 = flat % 40;
  int rest = flat / 40;
  int Y = rest % 160;
  int e = rest / 160;
  int X0 = x4 * 4;
  int a = (Y >= 80) ? 1 : 0;
  int bq = (X0 >= 80) ? 1 : 0;
  int yy = Y - a * 80, xx = X0 - bq * 80;
  int pi = yy / 20, y = yy - pi * 20;
  int pj = xx / 20, x0 = xx - pj * 20;
  int img = a * 2 + bq;
  int nn = img * 16 + pi * 4 + pj;
  int s0 = y * 20 + x0;
  float4 l4 = *(const float4*)(xin + ((img * 256 + e) * 80 + yy) * 80 + xx);
  float4 i4 = *(const float4*)(imp + nn * 400 + s0);
  const float* g = xin + (4 * 256 + e) * 6400;
  float4 u4 = up4(g, Y, X0);
  float4 o;
  o.x = l4.x * (0.6f * i4.x) + 0.5f * u4.x;
  o.y = l4.y * (0.6f * i4.y) + 0.5f * u4.y;
  o.z = l4.z * (0.6f * i4.z) + 0.5f * u4.z;
  o.w = l4.w * (0.6f * i4.w) + 0.5f * u4.w;
  *(float4*)(out + (e * 160 + Y) * 160 + X0) = o;
}

// ---------- launch ----------
extern "C" void kernel_launch(void* const* d_in, const int* in_sizes, int n_in,
                              void* d_out, int out_size, void* d_ws, size_t ws_size,
                              hipStream_t stream) {
  const float* x      = (const float*)d_in[0];   // [5,256,80,80]
  const float* W      = (const float*)d_in[1];   // [768,256]
  const float* bvec   = (const float*)d_in[2];   // [768]
  const float* sal_w  = (const float*)d_in[3];
  const float* sal_b  = (const float*)d_in[4];
  float* out = (float*)d_out;                    // [256,160,160]

  // ws layout (all offsets 16B-aligned)
  const size_t POS_OFF = 0;                         // 256*400*4      =   409600
  const size_t QF_OFF  = 409600;                    // 64*256*400*2   = 13107200
  const size_t KF_OFF  = QF_OFF + 13107200;
  const size_t QP_OFF  = KF_OFF + 13107200;
  const size_t KP_OFF  = QP_OFF + 13107200;
  const size_t CS_OFF  = KP_OFF + 13107200;         // 2*512*400*4    =  1638400
  const size_t IMP_OFF = CS_OFF + 1638400;          // 64*400*4       =   102400
  const size_t NEED    = IMP_OFF + 102400;          // 54,579,200 B
  if (ws_size < NEED) return;   // insufficient scratch: leave output poisoned (clean fail)

  char* ws = (char*)d_ws;
  float* pos    = (float*)(ws + POS_OFF);
  u16*   qf     = (u16*)(ws + QF_OFF);
  u16*   kf     = (u16*)(ws + KF_OFF);
  u16*   qp     = (u16*)(ws + QP_OFF);
  u16*   kp     = (u16*)(ws + KP_OFF);
  float* colsum2= (float*)(ws + CS_OFF);
  float* imp    = (float*)(ws + IMP_OFF);

  pos_kernel<<<400, 256, 0, stream>>>(pos);
  feat_kernel<<<dim3(6400, 2), 256, 0, stream>>>(x, pos, qf, kf);
  proj_kernel<<<dim3(256, 2), 256, 0, stream>>>(qf, kf, W, bvec, qp, kp);
  attn_kernel<<<dim3(512, 2), 256, 0, stream>>>(qp, kp, colsum2);
  imp_kernel<<<100, 256, 0, stream>>>(colsum2, sal_w, sal_b, imp);
  out_kernel<<<6400, 256, 0, stream>>>(x, imp, out);
}